// Round 1
// baseline (60.220 us; speedup 1.0000x reference)
//
#include <hip/hip_runtime.h>
#include <hip/hip_bf16.h>

// okl = log_C_kappa + kappa + mean_j log( sum_i exp(kappa*<mu_n_i,z_j> - kappa) )
//       - log(M) - log_C_zero
// M = 2048 components, J = M*n = 65536 sample columns, d = 32.

typedef __attribute__((ext_vector_type(8))) short bf16x8;
typedef __attribute__((ext_vector_type(4))) float f32x4;
typedef __attribute__((ext_vector_type(8))) unsigned short u16x8;

static __device__ __forceinline__ unsigned short f2bf(float f) {
  unsigned int u = __float_as_uint(f);
  u += 0x7FFFu + ((u >> 16) & 1u);   // round-to-nearest-even
  return (unsigned short)(u >> 16);
}

// Kernel 1: Abf = bf16(kappa * mu / ||mu||), shape [M, 32]
__global__ __launch_bounds__(256) void vmf_prep(const float* __restrict__ mu,
                                                const float* __restrict__ kp,
                                                unsigned short* __restrict__ Abf,
                                                int M) {
  int row = blockIdx.x * 256 + threadIdx.x;
  if (row >= M) return;
  const float4* m4 = (const float4*)(mu + (size_t)row * 32);
  float4 v[8];
  float ss = 0.f;
#pragma unroll
  for (int i = 0; i < 8; ++i) {
    v[i] = m4[i];
    ss += v[i].x * v[i].x + v[i].y * v[i].y + v[i].z * v[i].z + v[i].w * v[i].w;
  }
  float sc = kp[0] / sqrtf(ss);
  u16x8 o[4];
#pragma unroll
  for (int i = 0; i < 8; ++i) {
    o[i >> 1][(i & 1) * 4 + 0] = f2bf(v[i].x * sc);
    o[i >> 1][(i & 1) * 4 + 1] = f2bf(v[i].y * sc);
    o[i >> 1][(i & 1) * 4 + 2] = f2bf(v[i].z * sc);
    o[i >> 1][(i & 1) * 4 + 3] = f2bf(v[i].w * sc);
  }
  u16x8* dst = (u16x8*)(Abf + (size_t)row * 32);
#pragma unroll
  for (int i = 0; i < 4; ++i) dst[i] = o[i];
}

// Kernel 2: per wave, 2 N-tiles (32 columns). MFMA over all M rows with
// fixed-shift (kappa) online exp-sum; per-column log; wave-reduce; one
// partial per wave.
__global__ __launch_bounds__(256) void vmf_main(const unsigned short* __restrict__ Abf,
                                                const float* __restrict__ z,
                                                const float* __restrict__ kp,
                                                float* __restrict__ part,
                                                int M) {
  const int lane = threadIdx.x & 63;
  const int wave = threadIdx.x >> 6;
  const int r = lane & 15;   // row (A) / col (B) within tile
  const int q = lane >> 4;   // k-octet quadrant
  const float kap = kp[0];
  const int colbase = blockIdx.x * 128 + wave * 32;

  // Loop-invariant B fragments, fp32 -> bf16 on the fly.
  const float* z0p = z + (size_t)(colbase + r) * 32 + q * 8;
  const float* z1p = z + (size_t)(colbase + 16 + r) * 32 + q * 8;
  float4 f0a = *(const float4*)(z0p), f0b = *(const float4*)(z0p + 4);
  float4 f1a = *(const float4*)(z1p), f1b = *(const float4*)(z1p + 4);
  bf16x8 b0, b1;
  b0[0] = (short)f2bf(f0a.x); b0[1] = (short)f2bf(f0a.y);
  b0[2] = (short)f2bf(f0a.z); b0[3] = (short)f2bf(f0a.w);
  b0[4] = (short)f2bf(f0b.x); b0[5] = (short)f2bf(f0b.y);
  b0[6] = (short)f2bf(f0b.z); b0[7] = (short)f2bf(f0b.w);
  b1[0] = (short)f2bf(f1a.x); b1[1] = (short)f2bf(f1a.y);
  b1[2] = (short)f2bf(f1a.z); b1[3] = (short)f2bf(f1a.w);
  b1[4] = (short)f2bf(f1b.x); b1[5] = (short)f2bf(f1b.y);
  b1[6] = (short)f2bf(f1b.z); b1[7] = (short)f2bf(f1b.w);

  const unsigned short* ap = Abf + (size_t)r * 32 + q * 8;
  float acc0 = 0.f, acc1 = 0.f;
  const f32x4 zero = {0.f, 0.f, 0.f, 0.f};
#pragma unroll 2
  for (int m = 0; m < M; m += 16) {
    bf16x8 a = *(const bf16x8*)(ap + (size_t)m * 32);
    f32x4 c0 = __builtin_amdgcn_mfma_f32_16x16x32_bf16(a, b0, zero, 0, 0, 0);
    f32x4 c1 = __builtin_amdgcn_mfma_f32_16x16x32_bf16(a, b1, zero, 0, 0, 0);
#pragma unroll
    for (int t = 0; t < 4; ++t) {
      acc0 += __expf(c0[t] - kap);
      acc1 += __expf(c1[t] - kap);
    }
  }

  // Sum the 4 row-quadrants per column (lanes l, l^16, l^32, l^48 share col).
  acc0 += __shfl_xor(acc0, 16); acc0 += __shfl_xor(acc0, 32);
  acc1 += __shfl_xor(acc1, 16); acc1 += __shfl_xor(acc1, 32);
  float s = __logf(acc0) + __logf(acc1);   // t_j for this lane's 2 columns (x4 replicated)
  s += __shfl_xor(s, 1);  s += __shfl_xor(s, 2);
  s += __shfl_xor(s, 4);  s += __shfl_xor(s, 8);
  s += __shfl_xor(s, 16); s += __shfl_xor(s, 32);
  // s = 4 * sum over this wave's 32 columns of t_j
  if (lane == 0) part[blockIdx.x * 4 + wave] = s * 0.25f;
}

// Kernel 3: reduce per-wave partials, apply constants.
__global__ __launch_bounds__(256) void vmf_final(const float* __restrict__ part, int n,
                                                 const float* __restrict__ kp,
                                                 const float* __restrict__ lck,
                                                 const float* __restrict__ lc0,
                                                 float* __restrict__ out,
                                                 int M, int J) {
  __shared__ float red[256];
  float s = 0.f;
  for (int i = threadIdx.x; i < n; i += 256) s += part[i];
  red[threadIdx.x] = s;
  __syncthreads();
  for (int off = 128; off > 0; off >>= 1) {
    if (threadIdx.x < off) red[threadIdx.x] += red[threadIdx.x + off];
    __syncthreads();
  }
  if (threadIdx.x == 0) {
    float tbar = red[0] / (float)J;
    out[0] = lck[0] + kp[0] + tbar - logf((float)M) - lc0[0];
  }
}

extern "C" void kernel_launch(void* const* d_in, const int* in_sizes, int n_in,
                              void* d_out, int out_size, void* d_ws, size_t ws_size,
                              hipStream_t stream) {
  const float* mu  = (const float*)d_in[0];
  const float* z   = (const float*)d_in[1];
  const float* kp  = (const float*)d_in[2];
  const float* lck = (const float*)d_in[3];
  const float* lc0 = (const float*)d_in[4];
  const int M = in_sizes[0] / 32;   // 2048
  const int J = in_sizes[1] / 32;   // 65536 (= M * n_samples)

  char* ws = (char*)d_ws;
  unsigned short* Abf = (unsigned short*)ws;                 // M*32*2 = 128 KB
  size_t abytes = ((size_t)M * 32 * 2 + 255) & ~(size_t)255;
  float* part = (float*)(ws + abytes);                       // nblk*4 floats

  vmf_prep<<<(M + 255) / 256, 256, 0, stream>>>(mu, kp, Abf, M);
  const int nblk = J / 128;  // 512 for the reference shape (J % 128 == 0)
  vmf_main<<<nblk, 256, 0, stream>>>(Abf, z, kp, part, M);
  vmf_final<<<1, 256, 0, stream>>>(part, nblk * 4, kp, lck, lc0, (float*)d_out, M, J);
}

// Round 2
// 33.483 us; speedup vs baseline: 1.7985x; 1.7985x over previous
//
#include <hip/hip_runtime.h>
#include <hip/hip_bf16.h>

// okl = log_C_kappa + kappa + mean_j log( sum_i exp(kappa*<mu_n_i,z_j> - kappa) )
//       - log(M) - log_C_zero
// M = 2048 components, J = M*n = 65536 sample columns, d = 32.
//
// A is pre-scaled by kappa*log2(e)/||mu||, the -kappa*log2(e) shift is folded
// into the MFMA C-operand, so the epilogue per element is exp2 + add only.

typedef __attribute__((ext_vector_type(8))) short bf16x8;
typedef __attribute__((ext_vector_type(4))) float f32x4;
typedef __attribute__((ext_vector_type(8))) unsigned short u16x8;

#define LOG2E 1.44269504088896340736f

#if __has_builtin(__builtin_amdgcn_exp2f)
#define EXP2(x) __builtin_amdgcn_exp2f(x)
#else
#define EXP2(x) exp2f(x)
#endif

static __device__ __forceinline__ unsigned short f2bf(float f) {
  unsigned int u = __float_as_uint(f);
  u += 0x7FFFu + ((u >> 16) & 1u);   // round-to-nearest-even
  return (unsigned short)(u >> 16);
}

// Kernel 1: Abf = bf16(kappa*log2e * mu / ||mu||), shape [M, 32]
__global__ __launch_bounds__(256) void vmf_prep(const float* __restrict__ mu,
                                                const float* __restrict__ kp,
                                                unsigned short* __restrict__ Abf,
                                                int M) {
  int row = blockIdx.x * 256 + threadIdx.x;
  if (row >= M) return;
  const float4* m4 = (const float4*)(mu + (size_t)row * 32);
  float4 v[8];
  float ss = 0.f;
#pragma unroll
  for (int i = 0; i < 8; ++i) {
    v[i] = m4[i];
    ss += v[i].x * v[i].x + v[i].y * v[i].y + v[i].z * v[i].z + v[i].w * v[i].w;
  }
  float sc = kp[0] * LOG2E / sqrtf(ss);
  u16x8 o[4];
#pragma unroll
  for (int i = 0; i < 8; ++i) {
    o[i >> 1][(i & 1) * 4 + 0] = f2bf(v[i].x * sc);
    o[i >> 1][(i & 1) * 4 + 1] = f2bf(v[i].y * sc);
    o[i >> 1][(i & 1) * 4 + 2] = f2bf(v[i].z * sc);
    o[i >> 1][(i & 1) * 4 + 3] = f2bf(v[i].w * sc);
  }
  u16x8* dst = (u16x8*)(Abf + (size_t)row * 32);
#pragma unroll
  for (int i = 0; i < 4; ++i) dst[i] = o[i];
}

// Kernel 2: block = 64 columns (4 MFMA N-tiles) x 8 waves; each wave covers
// M/8 rows. Per-column partial exp2-sums combined in LDS, log'd, block-reduced
// to one partial per block.
__global__ __launch_bounds__(512) void vmf_main(const unsigned short* __restrict__ Abf,
                                                const float* __restrict__ z,
                                                const float* __restrict__ kp,
                                                float* __restrict__ part,
                                                int M) {
  const int lane = threadIdx.x & 63;
  const int wave = threadIdx.x >> 6;   // 0..7
  const int r = lane & 15;             // row (A) / col (B) within tile
  const int q = lane >> 4;             // k-octet quadrant
  const float S = kp[0] * LOG2E;
  const f32x4 cinit = {-S, -S, -S, -S};
  const int colbase = blockIdx.x * 64;

  // Loop-invariant B fragments (4 tiles), fp32 -> bf16 on the fly.
  bf16x8 b0, b1, b2, b3;
  {
    const float* zp;
    float4 fa, fb;
#define LOADB(bb, t)                                                       \
    zp = z + (size_t)(colbase + (t)*16 + r) * 32 + q * 8;                  \
    fa = *(const float4*)zp; fb = *(const float4*)(zp + 4);                \
    bb[0] = (short)f2bf(fa.x); bb[1] = (short)f2bf(fa.y);                  \
    bb[2] = (short)f2bf(fa.z); bb[3] = (short)f2bf(fa.w);                  \
    bb[4] = (short)f2bf(fb.x); bb[5] = (short)f2bf(fb.y);                  \
    bb[6] = (short)f2bf(fb.z); bb[7] = (short)f2bf(fb.w);
    LOADB(b0, 0) LOADB(b1, 1) LOADB(b2, 2) LOADB(b3, 3)
#undef LOADB
  }

  const int mchunk = M >> 3;           // rows per wave (256)
  const unsigned short* ap = Abf + (size_t)(wave * mchunk + r) * 32 + q * 8;
  float a0 = 0.f, a1 = 0.f, a2 = 0.f, a3 = 0.f;
#pragma unroll 2
  for (int m = 0; m < mchunk; m += 16) {
    bf16x8 av = *(const bf16x8*)(ap + (size_t)m * 32);
    f32x4 c0 = __builtin_amdgcn_mfma_f32_16x16x32_bf16(av, b0, cinit, 0, 0, 0);
    f32x4 c1 = __builtin_amdgcn_mfma_f32_16x16x32_bf16(av, b1, cinit, 0, 0, 0);
    f32x4 c2 = __builtin_amdgcn_mfma_f32_16x16x32_bf16(av, b2, cinit, 0, 0, 0);
    f32x4 c3 = __builtin_amdgcn_mfma_f32_16x16x32_bf16(av, b3, cinit, 0, 0, 0);
    a0 += (EXP2(c0[0]) + EXP2(c0[1])) + (EXP2(c0[2]) + EXP2(c0[3]));
    a1 += (EXP2(c1[0]) + EXP2(c1[1])) + (EXP2(c1[2]) + EXP2(c1[3]));
    a2 += (EXP2(c2[0]) + EXP2(c2[1])) + (EXP2(c2[2]) + EXP2(c2[3]));
    a3 += (EXP2(c3[0]) + EXP2(c3[1])) + (EXP2(c3[2]) + EXP2(c3[3]));
  }

  // Sum the 4 row-quadrants per column (lanes l, l^16, l^32, l^48 share col).
  a0 += __shfl_xor(a0, 16); a0 += __shfl_xor(a0, 32);
  a1 += __shfl_xor(a1, 16); a1 += __shfl_xor(a1, 32);
  a2 += __shfl_xor(a2, 16); a2 += __shfl_xor(a2, 32);
  a3 += __shfl_xor(a3, 16); a3 += __shfl_xor(a3, 32);

  // Lane l owns block-column l = (l>>4)*16 + (l&15): pick tile q's acc.
  float v = (q == 0) ? a0 : (q == 1) ? a1 : (q == 2) ? a2 : a3;
  __shared__ float red[8][64];
  red[wave][lane] = v;
  __syncthreads();

  if (wave == 0) {
    float s = 0.f;
#pragma unroll
    for (int w = 0; w < 8; ++w) s += red[w][lane];
    s = fmaxf(s, 1e-38f);
    float t = __logf(s);               // t_j for this block-column
    t += __shfl_xor(t, 1);  t += __shfl_xor(t, 2);
    t += __shfl_xor(t, 4);  t += __shfl_xor(t, 8);
    t += __shfl_xor(t, 16); t += __shfl_xor(t, 32);
    if (lane == 0) part[blockIdx.x] = t;
  }
}

// Kernel 3: reduce per-block partials, apply constants.
__global__ __launch_bounds__(256) void vmf_final(const float* __restrict__ part, int n,
                                                 const float* __restrict__ kp,
                                                 const float* __restrict__ lck,
                                                 const float* __restrict__ lc0,
                                                 float* __restrict__ out,
                                                 int M, int J) {
  __shared__ float red[256];
  float s = 0.f;
  for (int i = threadIdx.x; i < n; i += 256) s += part[i];
  red[threadIdx.x] = s;
  __syncthreads();
  for (int off = 128; off > 0; off >>= 1) {
    if (threadIdx.x < off) red[threadIdx.x] += red[threadIdx.x + off];
    __syncthreads();
  }
  if (threadIdx.x == 0) {
    float tbar = red[0] / (float)J;
    out[0] = lck[0] + kp[0] + tbar - logf((float)M) - lc0[0];
  }
}

extern "C" void kernel_launch(void* const* d_in, const int* in_sizes, int n_in,
                              void* d_out, int out_size, void* d_ws, size_t ws_size,
                              hipStream_t stream) {
  const float* mu  = (const float*)d_in[0];
  const float* z   = (const float*)d_in[1];
  const float* kp  = (const float*)d_in[2];
  const float* lck = (const float*)d_in[3];
  const float* lc0 = (const float*)d_in[4];
  const int M = in_sizes[0] / 32;   // 2048
  const int J = in_sizes[1] / 32;   // 65536 (= M * n_samples)

  char* ws = (char*)d_ws;
  unsigned short* Abf = (unsigned short*)ws;                 // M*32*2 = 128 KB
  size_t abytes = ((size_t)M * 32 * 2 + 255) & ~(size_t)255;
  float* part = (float*)(ws + abytes);                       // nblk floats

  vmf_prep<<<(M + 255) / 256, 256, 0, stream>>>(mu, kp, Abf, M);
  const int nblk = J / 64;  // 1024 blocks, 8 waves each
  vmf_main<<<nblk, 512, 0, stream>>>(Abf, z, kp, part, M);
  vmf_final<<<1, 256, 0, stream>>>(part, nblk, kp, lck, lc0, (float*)d_out, M, J);
}